// Round 1
// baseline (1166.759 us; speedup 1.0000x reference)
//
#include <hip/hip_runtime.h>
#include <math.h>

// ---------------------------------------------------------------------------
// SpectralConv2d: sigma = tensor-spectral-norm(w) via 20 complex power its,
// then y = conv2d_same(x, w/sigma, NHWC, 3x3) + bias.
// B=32 H=W=64 CIN=COUT=256 KH=KW=3.
// ---------------------------------------------------------------------------

#define EPSN 1e-12f

// ---- workspace layout (bytes) ----
// xb  : bf16 padded input  [32][66][66][256]          = 71,368,704 B
// wt  : bf16 weights       [9][256][256] (tap,o,ci)   =  1,179,648 B
// ctrl: float control area                            =    135,168 B
#define XB_OFF   0
#define WT_OFF   71368704
#define CTRL_OFF 72548352

// ctrl offsets (floats)
#define CTRL_M   0      // M[2][18]   (2 parity slots, 9 complex each)
#define CTRL_C   36     // c[2][6]
#define CTRL_D   48     // d[2][6]
#define CTRL_A   64     // a_raw[256] complex
#define CTRL_NA  576    // sum |a|^2 (final)
#define CTRL_PB  1024   // pb[64][256] complex  (per-block partial b)

struct c2 { float x, y; };
__device__ inline c2 cadd(c2 a, c2 b) { return {a.x + b.x, a.y + b.y}; }
__device__ inline c2 cmul(c2 a, c2 b) { return {a.x * b.x - a.y * b.y, a.x * b.y + a.y * b.x}; }
__device__ inline c2 cjg(c2 a) { return {a.x, -a.y}; }
__device__ inline c2 cscale(c2 a, float s) { return {a.x * s, a.y * s}; }

__device__ inline unsigned short f2bf(float f) {  // RNE fp32->bf16
    unsigned int u = __float_as_uint(f);
    unsigned int r = u + 0x7fffu + ((u >> 16) & 1u);
    return (unsigned short)(r >> 16);
}

typedef __bf16 bf16x8 __attribute__((ext_vector_type(8)));
typedef float  f32x4  __attribute__((ext_vector_type(4)));

// ---------------------------------------------------------------------------
// xprep: x fp32 NHWC -> padded bf16 [32][66][66][256]; also zero ctrl M[0], na
// grid: 34848 x 256 ; each thread handles 4 channels of one padded pixel
// ---------------------------------------------------------------------------
__global__ __launch_bounds__(256) void k_xprep(const float* __restrict__ x,
                                               unsigned short* __restrict__ xb,
                                               float* __restrict__ ctrl) {
    int flat = blockIdx.x * 256 + threadIdx.x;      // (b,hh,ww,c4), c4 innermost
    int c4   = flat & 63;
    int rest = flat >> 6;                           // (b*66+hh)*66+ww
    int ww   = rest % 66;
    int r2   = rest / 66;
    int hh   = r2 % 66;
    int b    = r2 / 66;
    int h = hh - 1, w2 = ww - 1;
    ushort4 outv;
    if (h >= 0 && h < 64 && w2 >= 0 && w2 < 64) {
        const float4 v = *(const float4*)(x + ((((b << 6) + h) << 6) + w2) * 256 + (c4 << 2));
        outv.x = f2bf(v.x); outv.y = f2bf(v.y); outv.z = f2bf(v.z); outv.w = f2bf(v.w);
    } else {
        outv.x = 0; outv.y = 0; outv.z = 0; outv.w = 0;
    }
    *(ushort4*)(xb + ((size_t)rest << 8) + (c4 << 2)) = outv;
    if (flat == 0) {
        #pragma unroll
        for (int j = 0; j < 18; ++j) ctrl[CTRL_M + j] = 0.f;   // M slot 0 for P(0)
        ctrl[CTRL_NA] = 0.f;
    }
}

// ---------------------------------------------------------------------------
// P(t): [t>0: b_{t-1}=normalize(sum_p pb); a_{t-1}=sum_i conj(b_i) g(t-1)
//        (g recomputed from K,c_{t-1},d_{t-1})]  else a,b = u1,u2 raw.
// Writes a_raw; accumulates M(t)=K·(ā,b̄) into M slot t&1 via atomics.
// grid: 64 x 1024 ; thread = (o = bid*4 + tid>>8, i = tid&255)
// ---------------------------------------------------------------------------
__global__ __launch_bounds__(1024) void k_p(const float* __restrict__ w,
                                            const float* __restrict__ u1,
                                            const float* __restrict__ u2,
                                            float* __restrict__ ctrl,
                                            int t, int isFinal) {
    const int tid  = threadIdx.x, bid = blockIdx.x;
    const int os   = tid >> 8, i = tid & 255;
    const int o    = (bid << 2) + os;
    const int lane = tid & 63, wid = tid >> 6;

    __shared__ float red1[16];
    __shared__ c2    red2[16];
    __shared__ c2    abc[4];
    __shared__ float mred[16][18];
    __shared__ float nbshare;

    c2 b_c, a_c;

    if (t == 0) {
        b_c = ((const c2*)u2)[i];
    } else {
        // b = normalize over i of sum_p pb[p][i]
        c2 s = {0.f, 0.f};
        const c2* pb = (const c2*)(ctrl + CTRL_PB);
        #pragma unroll 8
        for (int p = 0; p < 64; ++p) s = cadd(s, pb[(p << 8) + i]);
        float n2 = s.x * s.x + s.y * s.y;
        #pragma unroll
        for (int off = 32; off; off >>= 1) n2 += __shfl_down(n2, off);
        if (lane == 0) red1[wid] = n2;
        __syncthreads();
        if (tid == 0) {
            float acc = 0.f;
            #pragma unroll
            for (int k = 0; k < 16; ++k) acc += red1[k];
            nbshare = sqrtf(acc * 0.25f);   // 4 redundant copies per i
        }
        __syncthreads();
        float inv = 1.f / (nbshare + EPSN);
        b_c = cscale(s, inv);
    }

    // K row (9 reals)
    float kr[9];
    {
        const float* wr = w + ((size_t)((o << 8) + i)) * 9;
        #pragma unroll
        for (int j = 0; j < 9; ++j) kr[j] = wr[j];
    }

    if (t == 0) {
        a_c = ((const c2*)u1)[o];
        if (i == 0) ((c2*)(ctrl + CTRL_A))[o] = a_c;
    } else {
        // recompute g(t-1) = sum_hw K * conj(c_{t-1,h} d_{t-1,w})
        const int sl = (t - 1) & 1;
        c2 cc[3], dd[3];
        #pragma unroll
        for (int h = 0; h < 3; ++h) {
            cc[h] = {ctrl[CTRL_C + sl * 6 + 2 * h], ctrl[CTRL_C + sl * 6 + 2 * h + 1]};
            dd[h] = {ctrl[CTRL_D + sl * 6 + 2 * h], ctrl[CTRL_D + sl * 6 + 2 * h + 1]};
        }
        c2 g = {0.f, 0.f};
        #pragma unroll
        for (int h = 0; h < 3; ++h)
            #pragma unroll
            for (int w2 = 0; w2 < 3; ++w2) {
                c2 qv = cjg(cmul(cc[h], dd[w2]));
                g.x += kr[h * 3 + w2] * qv.x;
                g.y += kr[h * 3 + w2] * qv.y;
            }
        c2 contrib = cmul(cjg(b_c), g);
        float vx = contrib.x, vy = contrib.y;
        #pragma unroll
        for (int off = 32; off; off >>= 1) { vx += __shfl_down(vx, off); vy += __shfl_down(vy, off); }
        if (lane == 0) red2[wid] = {vx, vy};
        __syncthreads();
        if (tid < 4) {
            c2 s2 = {0.f, 0.f};
            #pragma unroll
            for (int k = 0; k < 4; ++k) s2 = cadd(s2, red2[tid * 4 + k]);
            abc[tid] = s2;
        }
        __syncthreads();
        a_c = abc[os];
        if (i == 0) {
            ((c2*)(ctrl + CTRL_A))[o] = a_c;
            if (isFinal) atomicAdd(ctrl + CTRL_NA, a_c.x * a_c.x + a_c.y * a_c.y);
        }
    }

    // M(t)[hw] += kr[hw] * conj(a*b)
    c2 pc = cjg(cmul(a_c, b_c));
    float mv[18];
    #pragma unroll
    for (int hw = 0; hw < 9; ++hw) { mv[2 * hw] = kr[hw] * pc.x; mv[2 * hw + 1] = kr[hw] * pc.y; }
    #pragma unroll
    for (int j = 0; j < 18; ++j)
        #pragma unroll
        for (int off = 32; off; off >>= 1) mv[j] += __shfl_down(mv[j], off);
    if (lane == 0) {
        #pragma unroll
        for (int j = 0; j < 18; ++j) mred[wid][j] = mv[j];
    }
    __syncthreads();
    if (tid < 18) {
        float s3 = 0.f;
        #pragma unroll
        for (int k = 0; k < 16; ++k) s3 += mred[k][tid];
        atomicAdd(ctrl + CTRL_M + (t & 1) * 18 + tid, s3);
    }
}

// ---------------------------------------------------------------------------
// Q(t): d_t=N(M^T c̄_{t-1}); c_t=N(M d̄_t); g=K·(c̄_t,d̄_t);
//       pb[bid][i] = sum_{os} conj(a_raw[o])*g . Zeroes M slot (t+1)&1.
// ---------------------------------------------------------------------------
__global__ __launch_bounds__(1024) void k_q(const float* __restrict__ w,
                                            const float* __restrict__ u3,
                                            float* __restrict__ ctrl, int t) {
    const int tid = threadIdx.x, bid = blockIdx.x;
    const int os  = tid >> 8, i = tid & 255;
    const int o   = (bid << 2) + os;
    __shared__ c2 gred[4][256];

    const int sl = t & 1;
    float m[18];
    #pragma unroll
    for (int j = 0; j < 18; ++j) m[j] = ctrl[CTRL_M + sl * 18 + j];

    c2 cc[3];
    if (t == 0) {
        #pragma unroll
        for (int h = 0; h < 3; ++h) cc[h] = ((const c2*)u3)[h];
    } else {
        const int cs = (t - 1) & 1;
        #pragma unroll
        for (int h = 0; h < 3; ++h)
            cc[h] = {ctrl[CTRL_C + cs * 6 + 2 * h], ctrl[CTRL_C + cs * 6 + 2 * h + 1]};
    }

    // d = N( sum_h M[h][w] conj(c_h) )
    c2 dv[3]; float nd2 = 0.f;
    #pragma unroll
    for (int w2 = 0; w2 < 3; ++w2) {
        c2 s = {0.f, 0.f};
        #pragma unroll
        for (int h = 0; h < 3; ++h) {
            c2 mc = {m[2 * (h * 3 + w2)], m[2 * (h * 3 + w2) + 1]};
            s = cadd(s, cmul(mc, cjg(cc[h])));
        }
        dv[w2] = s; nd2 += s.x * s.x + s.y * s.y;
    }
    {
        float inv = 1.f / (sqrtf(nd2) + EPSN);
        #pragma unroll
        for (int w2 = 0; w2 < 3; ++w2) dv[w2] = cscale(dv[w2], inv);
    }
    // c_new = N( sum_w M[h][w] conj(d_w) )
    c2 cn[3]; float nc2 = 0.f;
    #pragma unroll
    for (int h = 0; h < 3; ++h) {
        c2 s = {0.f, 0.f};
        #pragma unroll
        for (int w2 = 0; w2 < 3; ++w2) {
            c2 mc = {m[2 * (h * 3 + w2)], m[2 * (h * 3 + w2) + 1]};
            s = cadd(s, cmul(mc, cjg(dv[w2])));
        }
        cn[h] = s; nc2 += s.x * s.x + s.y * s.y;
    }
    {
        float inv = 1.f / (sqrtf(nc2) + EPSN);
        #pragma unroll
        for (int h = 0; h < 3; ++h) cn[h] = cscale(cn[h], inv);
    }

    if (bid == 0 && tid == 0) {
        #pragma unroll
        for (int h = 0; h < 3; ++h) {
            ctrl[CTRL_C + sl * 6 + 2 * h]     = cn[h].x;
            ctrl[CTRL_C + sl * 6 + 2 * h + 1] = cn[h].y;
            ctrl[CTRL_D + sl * 6 + 2 * h]     = dv[h].x;
            ctrl[CTRL_D + sl * 6 + 2 * h + 1] = dv[h].y;
        }
    }
    if (bid == 0 && tid >= 32 && tid < 50)          // zero M slot for P(t+1)
        ctrl[CTRL_M + ((t + 1) & 1) * 18 + (tid - 32)] = 0.f;

    float kr[9];
    {
        const float* wr = w + ((size_t)((o << 8) + i)) * 9;
        #pragma unroll
        for (int j = 0; j < 9; ++j) kr[j] = wr[j];
    }
    c2 g = {0.f, 0.f};
    #pragma unroll
    for (int h = 0; h < 3; ++h)
        #pragma unroll
        for (int w2 = 0; w2 < 3; ++w2) {
            c2 qv = cjg(cmul(cn[h], dv[w2]));
            g.x += kr[h * 3 + w2] * qv.x;
            g.y += kr[h * 3 + w2] * qv.y;
        }
    c2 a  = ((const c2*)(ctrl + CTRL_A))[o];
    gred[os][i] = cmul(cjg(a), g);
    __syncthreads();
    if (tid < 256) {
        c2 s = cadd(cadd(gred[0][tid], gred[1][tid]), cadd(gred[2][tid], gred[3][tid]));
        ((c2*)(ctrl + CTRL_PB))[(bid << 8) + tid] = s;
    }
}

// ---------------------------------------------------------------------------
// wprep: sigma from M(20),c_19,na; Wt[tap][o][ci] = bf16(w * 1/sigma)
// grid: 256 x 256 (o = bid, ci = tid)
// ---------------------------------------------------------------------------
__global__ __launch_bounds__(256) void k_wprep(const float* __restrict__ w,
                                               float* __restrict__ ctrl,
                                               unsigned short* __restrict__ wt) {
    __shared__ float invsig;
    if (threadIdx.x == 0) {
        float m[18];
        #pragma unroll
        for (int j = 0; j < 18; ++j) m[j] = ctrl[CTRL_M + j];   // slot 0 = M(20)
        c2 cc[3];
        #pragma unroll
        for (int h = 0; h < 3; ++h)
            cc[h] = {ctrl[CTRL_C + 6 + 2 * h], ctrl[CTRL_C + 6 + 2 * h + 1]}; // c_19 slot 1
        c2 dv[3]; float nd2 = 0.f;
        #pragma unroll
        for (int w2 = 0; w2 < 3; ++w2) {
            c2 s = {0.f, 0.f};
            #pragma unroll
            for (int h = 0; h < 3; ++h) {
                c2 mc = {m[2 * (h * 3 + w2)], m[2 * (h * 3 + w2) + 1]};
                s = cadd(s, cmul(mc, cjg(cc[h])));
            }
            dv[w2] = s; nd2 += s.x * s.x + s.y * s.y;
        }
        float invd = 1.f / (sqrtf(nd2) + EPSN);
        #pragma unroll
        for (int w2 = 0; w2 < 3; ++w2) dv[w2] = cscale(dv[w2], invd);
        c2 sg = {0.f, 0.f};
        #pragma unroll
        for (int h = 0; h < 3; ++h)
            #pragma unroll
            for (int w2 = 0; w2 < 3; ++w2) {
                c2 mc = {m[2 * (h * 3 + w2)], m[2 * (h * 3 + w2) + 1]};
                sg = cadd(sg, cmul(mc, cjg(cmul(cc[h], dv[w2]))));
            }
        float na    = sqrtf(ctrl[CTRL_NA]);
        float sigma = sqrtf(sg.x * sg.x + sg.y * sg.y) / (na + EPSN);
        invsig = 1.f / sigma;
    }
    __syncthreads();
    const int o = blockIdx.x, ci = threadIdx.x;
    const float s = invsig;
    const float* wr = w + ((size_t)((o << 8) + ci)) * 9;
    #pragma unroll
    for (int j = 0; j < 9; ++j)
        wt[(j << 16) + (o << 8) + ci] = f2bf(wr[j] * s);
}

// ---------------------------------------------------------------------------
// conv: implicit GEMM, bf16 MFMA 16x16x32. Block = 128 pixels (2 rows) x 128
// couts; 4 waves, each 64x64 (4x4 frags). A/B fragments direct from global.
// grid: 2048 x 256.  bid = (b<<6) | (hp<<1) | nh
// ---------------------------------------------------------------------------
__global__ __launch_bounds__(256) void k_conv(const unsigned short* __restrict__ xb,
                                              const unsigned short* __restrict__ wt,
                                              const float* __restrict__ bias,
                                              float* __restrict__ y) {
    const int tid  = threadIdx.x, bid = blockIdx.x;
    const int lane = tid & 63, wid = tid >> 6;
    const int l15  = lane & 15, q = lane >> 4;
    const int b    = bid >> 6, hp = (bid >> 1) & 31, nh = bid & 1;
    const int h0   = hp << 1;
    const int mh   = (wid & 1) << 6;
    const int n_off = (nh << 7) + ((wid >> 1) << 6);

    int abase[4], bbase[4];
    #pragma unroll
    for (int ms = 0; ms < 4; ++ms) {
        int p = mh + ms * 16 + l15;
        int r = p >> 6, wc = p & 63;
        abase[ms] = ((b * 66 + h0 + r) * 66 + wc) * 256 + (q << 3);
    }
    #pragma unroll
    for (int ns = 0; ns < 4; ++ns)
        bbase[ns] = (n_off + ns * 16 + l15) * 256 + (q << 3);

    f32x4 acc[4][4];
    #pragma unroll
    for (int ms = 0; ms < 4; ++ms)
        #pragma unroll
        for (int ns = 0; ns < 4; ++ns) acc[ms][ns] = {0.f, 0.f, 0.f, 0.f};

    for (int cc = 0; cc < 8; ++cc) {
        const int cco = cc << 5;
        #pragma unroll
        for (int tap = 0; tap < 9; ++tap) {
            const int kh = tap / 3, kw = tap % 3;
            const int aoff = (kh * 66 + kw) * 256 + cco;
            bf16x8 av[4], bv[4];
            #pragma unroll
            for (int ms = 0; ms < 4; ++ms)
                av[ms] = *(const bf16x8*)(xb + abase[ms] + aoff);
            #pragma unroll
            for (int ns = 0; ns < 4; ++ns)
                bv[ns] = *(const bf16x8*)(wt + (tap << 16) + bbase[ns] + cco);
            #pragma unroll
            for (int ms = 0; ms < 4; ++ms)
                #pragma unroll
                for (int ns = 0; ns < 4; ++ns)
                    acc[ms][ns] = __builtin_amdgcn_mfma_f32_16x16x32_bf16(
                        av[ms], bv[ns], acc[ms][ns], 0, 0, 0);
        }
    }

    float bias_v[4];
    #pragma unroll
    for (int ns = 0; ns < 4; ++ns) bias_v[ns] = bias[n_off + (ns << 4) + l15];

    #pragma unroll
    for (int ms = 0; ms < 4; ++ms) {
        const int pb2 = mh + (ms << 4) + (q << 2);
        #pragma unroll
        for (int r2 = 0; r2 < 4; ++r2) {
            const int pr = pb2 + r2;
            const int h = h0 + (pr >> 6), wc = pr & 63;
            float* yr = y + ((((b << 6) + h) << 6) + wc) * 256 + n_off;
            #pragma unroll
            for (int ns = 0; ns < 4; ++ns)
                yr[(ns << 4) + l15] = acc[ms][ns][r2] + bias_v[ns];
        }
    }
}

// ---------------------------------------------------------------------------
extern "C" void kernel_launch(void* const* d_in, const int* in_sizes, int n_in,
                              void* d_out, int out_size, void* d_ws, size_t ws_size,
                              hipStream_t stream) {
    const float* x    = (const float*)d_in[0];
    const float* w    = (const float*)d_in[1];
    const float* bias = (const float*)d_in[2];
    const float* u1   = (const float*)d_in[3];   // complex64 interleaved
    const float* u2   = (const float*)d_in[4];
    const float* u3   = (const float*)d_in[5];
    float* y = (float*)d_out;

    char* ws = (char*)d_ws;
    unsigned short* xb = (unsigned short*)(ws + XB_OFF);
    unsigned short* wt = (unsigned short*)(ws + WT_OFF);
    float*          ct = (float*)(ws + CTRL_OFF);

    k_xprep<<<34848, 256, 0, stream>>>(x, xb, ct);
    for (int t = 0; t < 20; ++t) {
        k_p<<<64, 1024, 0, stream>>>(w, u1, u2, ct, t, 0);
        k_q<<<64, 1024, 0, stream>>>(w, u3, ct, t);
    }
    k_p<<<64, 1024, 0, stream>>>(w, u1, u2, ct, 20, 1);   // final: M(20) + ||a||
    k_wprep<<<256, 256, 0, stream>>>(w, ct, wt);
    k_conv<<<2048, 256, 0, stream>>>(xb, wt, bias, y);
}